// Round 1
// baseline (24513.214 us; speedup 1.0000x reference)
//
#include <hip/hip_runtime.h>
#include <hip/hip_bf16.h>
#include <hip/hip_cooperative_groups.h>
#include <math.h>

namespace cg = cooperative_groups;

#define T_STEPS 256
#define B_SZ 64
#define DIN 512
#define H_SZ 1024
#define CH_SZ 2048
#define G3 6144
#define DOUT 512
#define TB 16384

typedef __attribute__((ext_vector_type(4))) float f32x4;
typedef __attribute__((ext_vector_type(8))) short s16x8;
typedef __attribute__((ext_vector_type(4))) short s16x4;
typedef __attribute__((ext_vector_type(8))) __bf16 bf16x8;

__device__ __forceinline__ unsigned short f2bf(float f) {
  unsigned u = __builtin_bit_cast(unsigned, f);
  u += 0x7fffu + ((u >> 16) & 1u);   // RNE
  return (unsigned short)(u >> 16);
}
__device__ __forceinline__ float bf2f(unsigned short h) {
  unsigned u = ((unsigned)h) << 16;
  return __builtin_bit_cast(float, u);
}
__device__ __forceinline__ f32x4 mfma16(s16x8 a, s16x8 b, f32x4 c) {
  return __builtin_amdgcn_mfma_f32_16x16x32_bf16(
      __builtin_bit_cast(bf16x8, a), __builtin_bit_cast(bf16x8, b), c, 0, 0, 0);
}

// ---------------------------------------------------------------------------
// C[M,N] = act(A[M,K] @ B[N,K]^T + bias[N]); unchanged verified GEMM.
// ---------------------------------------------------------------------------
template<bool AF32, int ACT, bool OBF>
__global__ __launch_bounds__(256, 2)
void gemm_bt(const void* __restrict__ Ap, long lda,
             const unsigned short* __restrict__ Bp,
             const float* __restrict__ bias,
             float* __restrict__ Cf, unsigned short* __restrict__ Cb, long ldc,
             int K)
{
  __shared__ unsigned short sA[128 * 40];
  __shared__ unsigned short sB[128 * 40];
  const int tid  = threadIdx.x;
  const int lane = tid & 63;
  const int wave = tid >> 6;
  const int wm = wave & 1, wn = wave >> 1;
  const int l16 = lane & 15, quad = lane >> 4;
  const long m0 = (long)blockIdx.x * 128;
  const long n0 = (long)blockIdx.y * 128;
  const int srow = tid >> 1;
  const int sseg = (tid & 1) << 4;

  f32x4 acc[4][4] = {};

  for (int k0 = 0; k0 < K; k0 += 32) {
    if constexpr (AF32) {
      const float* A = (const float*)Ap + (m0 + srow) * lda + (k0 + sseg);
      f32x4 v0 = *(const f32x4*)(A + 0);
      f32x4 v1 = *(const f32x4*)(A + 4);
      f32x4 v2 = *(const f32x4*)(A + 8);
      f32x4 v3 = *(const f32x4*)(A + 12);
      s16x8 p0, p1;
      p0[0] = (short)f2bf(v0.x); p0[1] = (short)f2bf(v0.y);
      p0[2] = (short)f2bf(v0.z); p0[3] = (short)f2bf(v0.w);
      p0[4] = (short)f2bf(v1.x); p0[5] = (short)f2bf(v1.y);
      p0[6] = (short)f2bf(v1.z); p0[7] = (short)f2bf(v1.w);
      p1[0] = (short)f2bf(v2.x); p1[1] = (short)f2bf(v2.y);
      p1[2] = (short)f2bf(v2.z); p1[3] = (short)f2bf(v2.w);
      p1[4] = (short)f2bf(v3.x); p1[5] = (short)f2bf(v3.y);
      p1[6] = (short)f2bf(v3.z); p1[7] = (short)f2bf(v3.w);
      *(s16x8*)&sA[srow * 40 + sseg]     = p0;
      *(s16x8*)&sA[srow * 40 + sseg + 8] = p1;
    } else {
      const unsigned short* A = (const unsigned short*)Ap + (m0 + srow) * lda + (k0 + sseg);
      *(s16x8*)&sA[srow * 40 + sseg]     = *(const s16x8*)(A);
      *(s16x8*)&sA[srow * 40 + sseg + 8] = *(const s16x8*)(A + 8);
    }
    {
      const unsigned short* Bq = Bp + (n0 + srow) * (long)K + (k0 + sseg);
      *(s16x8*)&sB[srow * 40 + sseg]     = *(const s16x8*)(Bq);
      *(s16x8*)&sB[srow * 40 + sseg + 8] = *(const s16x8*)(Bq + 8);
    }
    __syncthreads();
    s16x8 af[4], bfr[4];
#pragma unroll
    for (int i = 0; i < 4; ++i) {
      af[i]  = *(const s16x8*)&sA[(wm * 64 + i * 16 + l16) * 40 + quad * 8];
      bfr[i] = *(const s16x8*)&sB[(wn * 64 + i * 16 + l16) * 40 + quad * 8];
    }
#pragma unroll
    for (int mi = 0; mi < 4; ++mi)
#pragma unroll
      for (int ni = 0; ni < 4; ++ni)
        acc[mi][ni] = mfma16(af[mi], bfr[ni], acc[mi][ni]);
    __syncthreads();
  }

#pragma unroll
  for (int mi = 0; mi < 4; ++mi) {
#pragma unroll
    for (int ni = 0; ni < 4; ++ni) {
      const long n = n0 + wn * 64 + ni * 16 + l16;
      const float bv = bias[n];
#pragma unroll
      for (int i = 0; i < 4; ++i) {
        const long m = m0 + wm * 64 + mi * 16 + quad * 4 + i;
        float v = acc[mi][ni][i] + bv;
        if constexpr (ACT == 1) v = v > 0.f ? v : expm1f(v);
        if constexpr (ACT == 2) v = fmaxf(v, 0.f) + log1pf(expf(-fabsf(v))) + 0.1f;
        if constexpr (OBF) Cb[m * ldc + n] = f2bf(v);
        else               Cf[m * ldc + n] = v;
      }
    }
  }
}

// ---------------------------------------------------------------------------
// Persistent GRU recurrence: ONE cooperative kernel runs all 256 steps.
// 256 blocks (1/CU) x 512 threads (8 waves = 4 batch-tiles x 2 K-halves).
// Each block owns 8 hidden units -> 24 Whh rows (r,z,n) held in LDS bf16
// for the entire kernel (98 KB, staged once from fp32 Whh).
// Per step: gh = h @ Whh_slice^T via MFMA, A-fragments read directly from
// the global bf16 h ping-pong buffer (L2-resident, no staging barriers),
// K-split partials reduced through a small LDS scratch, fused gate epilogue
// (h_old carried in a register: thread owns the same (m,j) every step),
// then one grid.sync().
// LDS: 24*2088*2 = 100224 B (row stride 2088 elems == m97 bank-alias class)
//    + scratch 8*24*16*4 = 12288 B  -> 112.5 KB, 1 block/CU.
// ---------------------------------------------------------------------------
#define GRU_BLOCKS 256
#define UPB 8
#define WROWS 24
#define WSTR 2088

__global__ __launch_bounds__(512, 2)
void gru_persist(const unsigned short* __restrict__ gxb,  // [T,64,6144] bf16
                 const float* __restrict__ Whh,            // [6144,2048] f32
                 const float* __restrict__ bhh,            // [6144] f32
                 float* __restrict__ hid,                  // [T,64,2048] f32 out
                 unsigned short* __restrict__ hA,          // [64,2048] bf16 ping
                 unsigned short* __restrict__ hB)          // [64,2048] bf16 pong
{
  __shared__ unsigned short sW[WROWS * WSTR];
  __shared__ float scr[8][24][16];
  const int tid  = threadIdx.x;
  const int lane = tid & 63;
  const int wave = tid >> 6;
  const int l16  = lane & 15, quad = lane >> 4;
  const int bt   = wave & 3;        // batch tile (16 rows)
  const int kh   = wave >> 2;       // K half (1024)
  const int jb   = blockIdx.x * UPB;

  // one-time stage: 24 rows of Whh (fp32 -> bf16) into LDS
  for (int wr = 0; wr < WROWS; ++wr) {
    const int gate = wr >> 3, u = wr & 7;
    const float* src = Whh + (long)(gate * CH_SZ + jb + u) * CH_SZ + tid * 4;
    f32x4 v = *(const f32x4*)src;
    s16x4 p;
    p[0] = (short)f2bf(v.x); p[1] = (short)f2bf(v.y);
    p[2] = (short)f2bf(v.z); p[3] = (short)f2bf(v.w);
    *(s16x4*)&sW[wr * WSTR + tid * 4] = p;
  }

  // per-thread epilogue constants: thread -> (batch row om, unit ou)
  const int om  = tid >> 3;          // 0..63
  const int ou  = tid & 7;           // 0..7
  const int oj  = jb + ou;
  const int obt = om >> 4, omi = om & 15;
  const float br_ = bhh[oj], bz_ = bhh[CH_SZ + oj], bn_ = bhh[2 * CH_SZ + oj];

  // B-fragment LDS pointers (fixed for whole kernel)
  const unsigned short* w0 = &sW[l16 * WSTR + kh * 1024 + quad * 8];            // rows 0..15: r0..7,z0..7
  const unsigned short* w1 = &sW[(16 + (l16 & 7)) * WSTR + kh * 1024 + quad * 8]; // rows 16..23: n0..7 (dup hi lanes)

  float ho = 0.f;                    // fp32 h_old register carry
  cg::grid_group grid = cg::this_grid();
  __syncthreads();

  for (int t = 0; t < T_STEPS; ++t) {
    // prefetch gate preactivations early; latency hides under MFMA loop
    const unsigned short* gxt = gxb + (long)t * (B_SZ * G3) + (long)om * G3 + oj;
    const unsigned short gxr = gxt[0];
    const unsigned short gxz = gxt[CH_SZ];
    const unsigned short gxn = gxt[2 * CH_SZ];

    if (t > 0) {
      const unsigned short* hp = (t & 1) ? hA : hB;   // buffer written at t-1
      const unsigned short* hbase = hp + (bt * 16 + l16) * CH_SZ + kh * 1024 + quad * 8;
      f32x4 a0 = {}, a1 = {};
#pragma unroll 4
      for (int s = 0; s < 32; ++s) {
        s16x8 af = *(const s16x8*)(hbase + s * 32);
        s16x8 b0 = *(const s16x8*)(w0 + s * 32);
        s16x8 b1 = *(const s16x8*)(w1 + s * 32);
        a0 = mfma16(af, b0, a0);
        a1 = mfma16(af, b1, a1);
      }
#pragma unroll
      for (int i = 0; i < 4; ++i) scr[wave][l16][quad * 4 + i] = a0[i];
      if (l16 < 8) {
#pragma unroll
        for (int i = 0; i < 4; ++i) scr[wave][16 + l16][quad * 4 + i] = a1[i];
      }
    }
    __syncthreads();

    float ghr = 0.f, ghz = 0.f, ghn = 0.f;
    if (t > 0) {
      ghr = scr[obt][ou][omi]      + scr[4 + obt][ou][omi];
      ghz = scr[obt][8 + ou][omi]  + scr[4 + obt][8 + ou][omi];
      ghn = scr[obt][16 + ou][omi] + scr[4 + obt][16 + ou][omi];
    }
    const float xr = bf2f(gxr), xz = bf2f(gxz), xn = bf2f(gxn);
    const float r = 1.f / (1.f + expf(-(xr + ghr + br_)));
    const float z = 1.f / (1.f + expf(-(xz + ghz + bz_)));
    const float n = tanhf(xn + r * (ghn + bn_));
    const float hv = (1.f - z) * n + z * ho;
    ho = hv;
    hid[(long)t * (B_SZ * CH_SZ) + (long)om * CH_SZ + oj] = hv;
    unsigned short* hnb = (t & 1) ? hB : hA;
    hnb[om * CH_SZ + oj] = f2bf(hv);

    __threadfence();   // device-scope release before grid barrier
    grid.sync();
  }
}

__global__ void cast_f32_bf16(const float* __restrict__ s, unsigned short* __restrict__ d, long n) {
  long i = ((long)blockIdx.x * blockDim.x + threadIdx.x) * 4;
  if (i + 3 < n) {
    f32x4 v = *(const f32x4*)(s + i);
    s16x4 p;
    p[0] = (short)f2bf(v.x); p[1] = (short)f2bf(v.y);
    p[2] = (short)f2bf(v.z); p[3] = (short)f2bf(v.w);
    *(s16x4*)(d + i) = p;
  }
}

extern "C" void kernel_launch(void* const* d_in, const int* in_sizes, int n_in,
                              void* d_out, int out_size, void* d_ws, size_t ws_size,
                              hipStream_t stream)
{
  const float* x    = (const float*)d_in[0];
  const float* We   = (const float*)d_in[1];
  const float* be   = (const float*)d_in[2];
  const float* Wih  = (const float*)d_in[3];
  const float* bih  = (const float*)d_in[4];
  const float* Whh  = (const float*)d_in[5];
  const float* bhh  = (const float*)d_in[6];
  const float* Wmu  = (const float*)d_in[7];
  const float* bmu  = (const float*)d_in[8];
  const float* Wsig = (const float*)d_in[9];
  const float* bsig = (const float*)d_in[10];

  float* out = (float*)d_out;
  float* mu  = out;
  float* sg  = out + (long)TB * DOUT;
  float* hid = out + 2L * TB * DOUT;

  // workspace layout (bf16 buffers); Whh no longer needs a cast (persistent
  // kernel stages fp32 Whh -> LDS bf16 itself)
  char* w = (char*)d_ws;
  unsigned short* Web  = (unsigned short*)w; w += (long)H_SZ * DIN * 2;
  unsigned short* Wihb = (unsigned short*)w; w += (long)G3 * H_SZ * 2;
  unsigned short* Wmub = (unsigned short*)w; w += (long)DOUT * H_SZ * 2;
  unsigned short* Wsgb = (unsigned short*)w; w += (long)DOUT * H_SZ * 2;
  unsigned short* xeb  = (unsigned short*)w; w += (long)TB * H_SZ * 2;
  unsigned short* gxb  = (unsigned short*)w; w += (long)TB * G3 * 2;
  unsigned short* hbA  = (unsigned short*)w; w += (long)B_SZ * CH_SZ * 2;
  unsigned short* hbB  = (unsigned short*)w; w += (long)B_SZ * CH_SZ * 2;

  auto cast = [&](const float* s, unsigned short* d, long n) {
    int blocks = (int)((n / 4 + 255) / 256);
    cast_f32_bf16<<<blocks, 256, 0, stream>>>(s, d, n);
  };
  cast(We,   Web,  (long)H_SZ * DIN);
  cast(Wih,  Wihb, (long)G3 * H_SZ);
  cast(Wmu,  Wmub, (long)DOUT * H_SZ);
  cast(Wsig, Wsgb, (long)DOUT * H_SZ);

  // enc: xe = elu(x @ We^T + be) -> bf16 [TB, H]
  gemm_bt<true, 1, true><<<dim3(TB / 128, H_SZ / 128), 256, 0, stream>>>(
      x, (long)DIN, Web, be, nullptr, xeb, (long)H_SZ, DIN);

  // gx = xe @ Wih^T + bih -> bf16 [TB, 6144]
  gemm_bt<false, 0, true><<<dim3(TB / 128, G3 / 128), 256, 0, stream>>>(
      xeb, (long)H_SZ, Wihb, bih, nullptr, gxb, (long)G3, H_SZ);

  // recurrence: single persistent cooperative kernel, grid.sync per step
  {
    void* kargs[] = {
      (void*)&gxb, (void*)&Whh, (void*)&bhh, (void*)&hid,
      (void*)&hbA, (void*)&hbB
    };
    hipLaunchCooperativeKernel((void*)gru_persist, dim3(GRU_BLOCKS), dim3(512),
                               kargs, 0, stream);
  }

  // heads: mu = elu(h_mu @ Wmu^T + bmu); sig = softplus(h_sig @ Wsig^T + bsig) + 0.1
  gemm_bt<true, 1, false><<<dim3(TB / 128, DOUT / 128), 256, 0, stream>>>(
      hid, (long)CH_SZ, Wmub, bmu, mu, nullptr, (long)DOUT, H_SZ);
  gemm_bt<true, 2, false><<<dim3(TB / 128, DOUT / 128), 256, 0, stream>>>(
      hid + H_SZ, (long)CH_SZ, Wsgb, bsig, sg, nullptr, (long)DOUT, H_SZ);
}

// Round 2
// 8864.333 us; speedup vs baseline: 2.7654x; 2.7654x over previous
//
#include <hip/hip_runtime.h>
#include <hip/hip_bf16.h>
#include <math.h>

#define T_STEPS 256
#define B_SZ 64
#define DIN 512
#define H_SZ 1024
#define CH_SZ 2048
#define G3 6144
#define DOUT 512
#define TB 16384

typedef __attribute__((ext_vector_type(4))) float f32x4;
typedef __attribute__((ext_vector_type(8))) short s16x8;
typedef __attribute__((ext_vector_type(4))) short s16x4;
typedef __attribute__((ext_vector_type(8))) __bf16 bf16x8;

__device__ __forceinline__ unsigned short f2bf(float f) {
  unsigned u = __builtin_bit_cast(unsigned, f);
  u += 0x7fffu + ((u >> 16) & 1u);   // RNE
  return (unsigned short)(u >> 16);
}
__device__ __forceinline__ float bf2f(unsigned short h) {
  unsigned u = ((unsigned)h) << 16;
  return __builtin_bit_cast(float, u);
}
__device__ __forceinline__ f32x4 mfma16(s16x8 a, s16x8 b, f32x4 c) {
  return __builtin_amdgcn_mfma_f32_16x16x32_bf16(
      __builtin_bit_cast(bf16x8, a), __builtin_bit_cast(bf16x8, b), c, 0, 0, 0);
}

// ---------------------------------------------------------------------------
// C[M,N] = act(A[M,K] @ B[N,K]^T + bias[N]); unchanged verified GEMM.
// ---------------------------------------------------------------------------
template<bool AF32, int ACT, bool OBF>
__global__ __launch_bounds__(256, 2)
void gemm_bt(const void* __restrict__ Ap, long lda,
             const unsigned short* __restrict__ Bp,
             const float* __restrict__ bias,
             float* __restrict__ Cf, unsigned short* __restrict__ Cb, long ldc,
             int K)
{
  __shared__ unsigned short sA[128 * 40];
  __shared__ unsigned short sB[128 * 40];
  const int tid  = threadIdx.x;
  const int lane = tid & 63;
  const int wave = tid >> 6;
  const int wm = wave & 1, wn = wave >> 1;
  const int l16 = lane & 15, quad = lane >> 4;
  const long m0 = (long)blockIdx.x * 128;
  const long n0 = (long)blockIdx.y * 128;
  const int srow = tid >> 1;
  const int sseg = (tid & 1) << 4;

  f32x4 acc[4][4] = {};

  for (int k0 = 0; k0 < K; k0 += 32) {
    if constexpr (AF32) {
      const float* A = (const float*)Ap + (m0 + srow) * lda + (k0 + sseg);
      f32x4 v0 = *(const f32x4*)(A + 0);
      f32x4 v1 = *(const f32x4*)(A + 4);
      f32x4 v2 = *(const f32x4*)(A + 8);
      f32x4 v3 = *(const f32x4*)(A + 12);
      s16x8 p0, p1;
      p0[0] = (short)f2bf(v0.x); p0[1] = (short)f2bf(v0.y);
      p0[2] = (short)f2bf(v0.z); p0[3] = (short)f2bf(v0.w);
      p0[4] = (short)f2bf(v1.x); p0[5] = (short)f2bf(v1.y);
      p0[6] = (short)f2bf(v1.z); p0[7] = (short)f2bf(v1.w);
      p1[0] = (short)f2bf(v2.x); p1[1] = (short)f2bf(v2.y);
      p1[2] = (short)f2bf(v2.z); p1[3] = (short)f2bf(v2.w);
      p1[4] = (short)f2bf(v3.x); p1[5] = (short)f2bf(v3.y);
      p1[6] = (short)f2bf(v3.z); p1[7] = (short)f2bf(v3.w);
      *(s16x8*)&sA[srow * 40 + sseg]     = p0;
      *(s16x8*)&sA[srow * 40 + sseg + 8] = p1;
    } else {
      const unsigned short* A = (const unsigned short*)Ap + (m0 + srow) * lda + (k0 + sseg);
      *(s16x8*)&sA[srow * 40 + sseg]     = *(const s16x8*)(A);
      *(s16x8*)&sA[srow * 40 + sseg + 8] = *(const s16x8*)(A + 8);
    }
    {
      const unsigned short* Bq = Bp + (n0 + srow) * (long)K + (k0 + sseg);
      *(s16x8*)&sB[srow * 40 + sseg]     = *(const s16x8*)(Bq);
      *(s16x8*)&sB[srow * 40 + sseg + 8] = *(const s16x8*)(Bq + 8);
    }
    __syncthreads();
    s16x8 af[4], bfr[4];
#pragma unroll
    for (int i = 0; i < 4; ++i) {
      af[i]  = *(const s16x8*)&sA[(wm * 64 + i * 16 + l16) * 40 + quad * 8];
      bfr[i] = *(const s16x8*)&sB[(wn * 64 + i * 16 + l16) * 40 + quad * 8];
    }
#pragma unroll
    for (int mi = 0; mi < 4; ++mi)
#pragma unroll
      for (int ni = 0; ni < 4; ++ni)
        acc[mi][ni] = mfma16(af[mi], bfr[ni], acc[mi][ni]);
    __syncthreads();
  }

#pragma unroll
  for (int mi = 0; mi < 4; ++mi) {
#pragma unroll
    for (int ni = 0; ni < 4; ++ni) {
      const long n = n0 + wn * 64 + ni * 16 + l16;
      const float bv = bias[n];
#pragma unroll
      for (int i = 0; i < 4; ++i) {
        const long m = m0 + wm * 64 + mi * 16 + quad * 4 + i;
        float v = acc[mi][ni][i] + bv;
        if constexpr (ACT == 1) v = v > 0.f ? v : expm1f(v);
        if constexpr (ACT == 2) v = fmaxf(v, 0.f) + log1pf(expf(-fabsf(v))) + 0.1f;
        if constexpr (OBF) Cb[m * ldc + n] = f2bf(v);
        else               Cf[m * ldc + n] = v;
      }
    }
  }
}

// ---------------------------------------------------------------------------
// Persistent GRU recurrence, hand-rolled grid barrier.
// 256 blocks (1/CU, cooperative launch guarantees co-residency) x 512 thr.
// Each block owns 8 hidden units -> 24 Whh rows LDS-resident (bf16) all run.
// Barrier: monotonic counter. Arrival = atomic add RELEASE/agent (one
// buffer_wbl2; dirty L2 per CU is only ~4 KB/step). Poll = RELAXED agent
// loads (sc1, no cache invalidation) + s_sleep. Exit = one ACQUIRE load
// (one buffer_inv) -> other XCDs' h stores become visible.
// LDS: sW 24x2050x2 = 98400 B (stride 1025 words == 1 mod 32, conflict-free)
//    + scr 8x24x17x4 = 13056 B -> 111.5 KB, 1 block/CU.
// ---------------------------------------------------------------------------
#define GRU_BLOCKS 256
#define UPB 8
#define WROWS 24
#define WSTR 2050

__global__ __launch_bounds__(512, 2)
void gru_persist(const unsigned short* __restrict__ gxb,  // [T,64,6144] bf16
                 const float* __restrict__ Whh,            // [6144,2048] f32
                 const float* __restrict__ bhh,             // [6144] f32
                 float* __restrict__ hid,                   // [T,64,2048] f32 out
                 unsigned short* __restrict__ hA,           // [64,2048] bf16 ping
                 unsigned short* __restrict__ hB,           // [64,2048] bf16 pong
                 unsigned* __restrict__ bar)                // barrier counter
{
  __shared__ unsigned short sW[WROWS * WSTR];
  __shared__ float scr[8][24][17];
  const int tid  = threadIdx.x;
  const int lane = tid & 63;
  const int wave = tid >> 6;
  const int l16  = lane & 15, quad = lane >> 4;
  const int bt   = wave & 3;        // batch tile (16 rows)
  const int kh   = wave >> 2;       // K half (1024)
  const int jb   = blockIdx.x * UPB;

  // one-time stage: 24 rows of Whh (fp32 -> bf16) into LDS
  for (int wr = 0; wr < WROWS; ++wr) {
    const int gate = wr >> 3, u = wr & 7;
    const float* src = Whh + (long)(gate * CH_SZ + jb + u) * CH_SZ + tid * 4;
    f32x4 v = *(const f32x4*)src;
    s16x4 p;
    p[0] = (short)f2bf(v.x); p[1] = (short)f2bf(v.y);
    p[2] = (short)f2bf(v.z); p[3] = (short)f2bf(v.w);
    *(s16x4*)&sW[wr * WSTR + tid * 4] = p;
  }

  // per-thread epilogue constants: thread -> (batch row om, unit ou)
  const int om  = tid >> 3;          // 0..63
  const int ou  = tid & 7;           // 0..7
  const int oj  = jb + ou;
  const int obt = om >> 4, omi = om & 15;
  const float br_ = bhh[oj], bz_ = bhh[CH_SZ + oj], bn_ = bhh[2 * CH_SZ + oj];

  // B-fragment LDS base pointers (fixed for whole kernel)
  const unsigned short* w0 = &sW[l16 * WSTR + kh * 1024 + quad * 8];              // rows 0..15: r0..7,z0..7
  const unsigned short* w1 = &sW[(16 + (l16 & 7)) * WSTR + kh * 1024 + quad * 8]; // rows 16..23: n0..7 (dup)

  float ho = 0.f;                    // fp32 h_old register carry
  __syncthreads();

  for (int t = 0; t < T_STEPS; ++t) {
    // prefetch gate preactivations early; latency hides under MFMA loop
    const unsigned short* gxt = gxb + (long)t * (B_SZ * G3) + (long)om * G3 + oj;
    const unsigned short gxr = gxt[0];
    const unsigned short gxz = gxt[CH_SZ];
    const unsigned short gxn = gxt[2 * CH_SZ];

    if (t > 0) {
      const unsigned short* hp = (t & 1) ? hA : hB;   // buffer written at t-1
      const unsigned short* hbase = hp + (bt * 16 + l16) * CH_SZ + kh * 1024 + quad * 8;
      f32x4 a0 = {}, a1 = {};
      // 4 chunks of 8 A-frags, depth-2 pipeline (~8 loads in flight)
      s16x8 A0[8], A1[8];
#pragma unroll
      for (int u = 0; u < 8; ++u) A0[u] = *(const s16x8*)(hbase + u * 32);
#pragma unroll
      for (int u = 0; u < 8; ++u) A1[u] = *(const s16x8*)(hbase + (8 + u) * 32);
#pragma unroll
      for (int u = 0; u < 8; ++u) {
        a0 = mfma16(A0[u], *(const s16x8*)(w0 + u * 32), a0);
        a1 = mfma16(A0[u], *(const s16x8*)(w1 + u * 32), a1);
      }
#pragma unroll
      for (int u = 0; u < 8; ++u) A0[u] = *(const s16x8*)(hbase + (16 + u) * 32);
#pragma unroll
      for (int u = 0; u < 8; ++u) {
        a0 = mfma16(A1[u], *(const s16x8*)(w0 + (8 + u) * 32), a0);
        a1 = mfma16(A1[u], *(const s16x8*)(w1 + (8 + u) * 32), a1);
      }
#pragma unroll
      for (int u = 0; u < 8; ++u) A1[u] = *(const s16x8*)(hbase + (24 + u) * 32);
#pragma unroll
      for (int u = 0; u < 8; ++u) {
        a0 = mfma16(A0[u], *(const s16x8*)(w0 + (16 + u) * 32), a0);
        a1 = mfma16(A0[u], *(const s16x8*)(w1 + (16 + u) * 32), a1);
      }
#pragma unroll
      for (int u = 0; u < 8; ++u) {
        a0 = mfma16(A1[u], *(const s16x8*)(w0 + (24 + u) * 32), a0);
        a1 = mfma16(A1[u], *(const s16x8*)(w1 + (24 + u) * 32), a1);
      }
#pragma unroll
      for (int i = 0; i < 4; ++i) scr[wave][l16][quad * 4 + i] = a0[i];
      if (l16 < 8) {
#pragma unroll
        for (int i = 0; i < 4; ++i) scr[wave][16 + l16][quad * 4 + i] = a1[i];
      }
    }
    __syncthreads();

    float ghr = 0.f, ghz = 0.f, ghn = 0.f;
    if (t > 0) {
      ghr = scr[obt][ou][omi]      + scr[4 + obt][ou][omi];
      ghz = scr[obt][8 + ou][omi]  + scr[4 + obt][8 + ou][omi];
      ghn = scr[obt][16 + ou][omi] + scr[4 + obt][16 + ou][omi];
    }
    const float xr = bf2f(gxr), xz = bf2f(gxz), xn = bf2f(gxn);
    const float r = 1.f / (1.f + expf(-(xr + ghr + br_)));
    const float z = 1.f / (1.f + expf(-(xz + ghz + bz_)));
    const float n = tanhf(xn + r * (ghn + bn_));
    const float hv = (1.f - z) * n + z * ho;
    ho = hv;
    hid[(long)t * (B_SZ * CH_SZ) + (long)om * CH_SZ + oj] = hv;
    unsigned short* hnb = (t & 1) ? hB : hA;
    hnb[om * CH_SZ + oj] = f2bf(hv);

    if (t < T_STEPS - 1) {
      // ---- lean grid barrier ----
      __syncthreads();                       // all block stores drained (vmcnt 0)
      if (tid == 0) {
        __hip_atomic_fetch_add(bar, 1u, __ATOMIC_RELEASE, __HIP_MEMORY_SCOPE_AGENT);
        const unsigned target = (unsigned)(t + 1) * GRU_BLOCKS;
        while (__hip_atomic_load(bar, __ATOMIC_RELAXED, __HIP_MEMORY_SCOPE_AGENT) < target)
          __builtin_amdgcn_s_sleep(1);
        (void)__hip_atomic_load(bar, __ATOMIC_ACQUIRE, __HIP_MEMORY_SCOPE_AGENT);
      }
      __syncthreads();
    }
  }
}

__global__ void cast_f32_bf16(const float* __restrict__ s, unsigned short* __restrict__ d, long n) {
  long i = ((long)blockIdx.x * blockDim.x + threadIdx.x) * 4;
  if (i + 3 < n) {
    f32x4 v = *(const f32x4*)(s + i);
    s16x4 p;
    p[0] = (short)f2bf(v.x); p[1] = (short)f2bf(v.y);
    p[2] = (short)f2bf(v.z); p[3] = (short)f2bf(v.w);
    *(s16x4*)(d + i) = p;
  }
}

__global__ void zero_u32(unsigned int* p, int n) {
  int i = blockIdx.x * blockDim.x + threadIdx.x;
  if (i < n) p[i] = 0u;
}

extern "C" void kernel_launch(void* const* d_in, const int* in_sizes, int n_in,
                              void* d_out, int out_size, void* d_ws, size_t ws_size,
                              hipStream_t stream)
{
  const float* x    = (const float*)d_in[0];
  const float* We   = (const float*)d_in[1];
  const float* be   = (const float*)d_in[2];
  const float* Wih  = (const float*)d_in[3];
  const float* bih  = (const float*)d_in[4];
  const float* Whh  = (const float*)d_in[5];
  const float* bhh  = (const float*)d_in[6];
  const float* Wmu  = (const float*)d_in[7];
  const float* bmu  = (const float*)d_in[8];
  const float* Wsig = (const float*)d_in[9];
  const float* bsig = (const float*)d_in[10];

  float* out = (float*)d_out;
  float* mu  = out;
  float* sg  = out + (long)TB * DOUT;
  float* hid = out + 2L * TB * DOUT;

  // workspace layout
  char* w = (char*)d_ws;
  unsigned short* Web  = (unsigned short*)w; w += (long)H_SZ * DIN * 2;
  unsigned short* Wihb = (unsigned short*)w; w += (long)G3 * H_SZ * 2;
  unsigned short* Wmub = (unsigned short*)w; w += (long)DOUT * H_SZ * 2;
  unsigned short* Wsgb = (unsigned short*)w; w += (long)DOUT * H_SZ * 2;
  unsigned short* xeb  = (unsigned short*)w; w += (long)TB * H_SZ * 2;
  unsigned short* gxb  = (unsigned short*)w; w += (long)TB * G3 * 2;
  unsigned short* hbA  = (unsigned short*)w; w += (long)B_SZ * CH_SZ * 2;
  unsigned short* hbB  = (unsigned short*)w; w += (long)B_SZ * CH_SZ * 2;
  unsigned*       bar  = (unsigned*)w;       w += 64;   // barrier counter

  auto cast = [&](const float* s, unsigned short* d, long n) {
    int blocks = (int)((n / 4 + 255) / 256);
    cast_f32_bf16<<<blocks, 256, 0, stream>>>(s, d, n);
  };
  cast(We,   Web,  (long)H_SZ * DIN);
  cast(Wih,  Wihb, (long)G3 * H_SZ);
  cast(Wmu,  Wmub, (long)DOUT * H_SZ);
  cast(Wsig, Wsgb, (long)DOUT * H_SZ);
  zero_u32<<<1, 64, 0, stream>>>((unsigned int*)bar, 16);  // re-zeroed every launch/replay

  // enc: xe = elu(x @ We^T + be) -> bf16 [TB, H]
  gemm_bt<true, 1, true><<<dim3(TB / 128, H_SZ / 128), 256, 0, stream>>>(
      x, (long)DIN, Web, be, nullptr, xeb, (long)H_SZ, DIN);

  // gx = xe @ Wih^T + bih -> bf16 [TB, 6144]
  gemm_bt<false, 0, true><<<dim3(TB / 128, G3 / 128), 256, 0, stream>>>(
      xeb, (long)H_SZ, Wihb, bih, nullptr, gxb, (long)G3, H_SZ);

  // recurrence: persistent kernel; cooperative launch only for co-residency
  {
    void* kargs[] = {
      (void*)&gxb, (void*)&Whh, (void*)&bhh, (void*)&hid,
      (void*)&hbA, (void*)&hbB, (void*)&bar
    };
    hipLaunchCooperativeKernel((void*)gru_persist, dim3(GRU_BLOCKS), dim3(512),
                               kargs, 0, stream);
  }

  // heads
  gemm_bt<true, 1, false><<<dim3(TB / 128, DOUT / 128), 256, 0, stream>>>(
      hid, (long)CH_SZ, Wmub, bmu, mu, nullptr, (long)DOUT, H_SZ);
  gemm_bt<true, 2, false><<<dim3(TB / 128, DOUT / 128), 256, 0, stream>>>(
      hid + H_SZ, (long)CH_SZ, Wsgb, bsig, sg, nullptr, (long)DOUT, H_SZ);
}

// Round 3
// 5505.376 us; speedup vs baseline: 4.4526x; 1.6101x over previous
//
#include <hip/hip_runtime.h>
#include <hip/hip_bf16.h>
#include <math.h>

#define T_STEPS 256
#define B_SZ 64
#define DIN 512
#define H_SZ 1024
#define CH_SZ 2048
#define G3 6144
#define DOUT 512
#define TB 16384

typedef __attribute__((ext_vector_type(4))) float f32x4;
typedef __attribute__((ext_vector_type(8))) short s16x8;
typedef __attribute__((ext_vector_type(4))) short s16x4;
typedef __attribute__((ext_vector_type(4))) unsigned u32x4;
typedef __attribute__((ext_vector_type(8))) __bf16 bf16x8;

__device__ __forceinline__ unsigned short f2bf(float f) {
  unsigned u = __builtin_bit_cast(unsigned, f);
  u += 0x7fffu + ((u >> 16) & 1u);   // RNE
  return (unsigned short)(u >> 16);
}
__device__ __forceinline__ float bf2f(unsigned short h) {
  unsigned u = ((unsigned)h) << 16;
  return __builtin_bit_cast(float, u);
}
__device__ __forceinline__ f32x4 mfma16(s16x8 a, s16x8 b, f32x4 c) {
  return __builtin_amdgcn_mfma_f32_16x16x32_bf16(
      __builtin_bit_cast(bf16x8, a), __builtin_bit_cast(bf16x8, b), c, 0, 0, 0);
}
// 8 fp32 -> 8 bf16 (RNE) packed, via v_cvt_pk_bf16_f32 (no builtin on gfx950)
__device__ __forceinline__ s16x8 cvt8(f32x4 lo, f32x4 hi) {
  unsigned r0, r1, r2, r3;
  asm("v_cvt_pk_bf16_f32 %0, %1, %2" : "=v"(r0) : "v"(lo.x), "v"(lo.y));
  asm("v_cvt_pk_bf16_f32 %0, %1, %2" : "=v"(r1) : "v"(lo.z), "v"(lo.w));
  asm("v_cvt_pk_bf16_f32 %0, %1, %2" : "=v"(r2) : "v"(hi.x), "v"(hi.y));
  asm("v_cvt_pk_bf16_f32 %0, %1, %2" : "=v"(r3) : "v"(hi.z), "v"(hi.w));
  u32x4 p; p[0] = r0; p[1] = r1; p[2] = r2; p[3] = r3;
  return __builtin_bit_cast(s16x8, p);
}

// ---------------------------------------------------------------------------
// C[M,N] = act(A[M,K] @ B[N,K]^T + bias[N]); unchanged verified GEMM.
// ---------------------------------------------------------------------------
template<bool AF32, int ACT, bool OBF>
__global__ __launch_bounds__(256, 2)
void gemm_bt(const void* __restrict__ Ap, long lda,
             const unsigned short* __restrict__ Bp,
             const float* __restrict__ bias,
             float* __restrict__ Cf, unsigned short* __restrict__ Cb, long ldc,
             int K)
{
  __shared__ unsigned short sA[128 * 40];
  __shared__ unsigned short sB[128 * 40];
  const int tid  = threadIdx.x;
  const int lane = tid & 63;
  const int wave = tid >> 6;
  const int wm = wave & 1, wn = wave >> 1;
  const int l16 = lane & 15, quad = lane >> 4;
  const long m0 = (long)blockIdx.x * 128;
  const long n0 = (long)blockIdx.y * 128;
  const int srow = tid >> 1;
  const int sseg = (tid & 1) << 4;

  f32x4 acc[4][4] = {};

  for (int k0 = 0; k0 < K; k0 += 32) {
    if constexpr (AF32) {
      const float* A = (const float*)Ap + (m0 + srow) * lda + (k0 + sseg);
      f32x4 v0 = *(const f32x4*)(A + 0);
      f32x4 v1 = *(const f32x4*)(A + 4);
      f32x4 v2 = *(const f32x4*)(A + 8);
      f32x4 v3 = *(const f32x4*)(A + 12);
      s16x8 p0, p1;
      p0[0] = (short)f2bf(v0.x); p0[1] = (short)f2bf(v0.y);
      p0[2] = (short)f2bf(v0.z); p0[3] = (short)f2bf(v0.w);
      p0[4] = (short)f2bf(v1.x); p0[5] = (short)f2bf(v1.y);
      p0[6] = (short)f2bf(v1.z); p0[7] = (short)f2bf(v1.w);
      p1[0] = (short)f2bf(v2.x); p1[1] = (short)f2bf(v2.y);
      p1[2] = (short)f2bf(v2.z); p1[3] = (short)f2bf(v2.w);
      p1[4] = (short)f2bf(v3.x); p1[5] = (short)f2bf(v3.y);
      p1[6] = (short)f2bf(v3.z); p1[7] = (short)f2bf(v3.w);
      *(s16x8*)&sA[srow * 40 + sseg]     = p0;
      *(s16x8*)&sA[srow * 40 + sseg + 8] = p1;
    } else {
      const unsigned short* A = (const unsigned short*)Ap + (m0 + srow) * lda + (k0 + sseg);
      *(s16x8*)&sA[srow * 40 + sseg]     = *(const s16x8*)(A);
      *(s16x8*)&sA[srow * 40 + sseg + 8] = *(const s16x8*)(A + 8);
    }
    {
      const unsigned short* Bq = Bp + (n0 + srow) * (long)K + (k0 + sseg);
      *(s16x8*)&sB[srow * 40 + sseg]     = *(const s16x8*)(Bq);
      *(s16x8*)&sB[srow * 40 + sseg + 8] = *(const s16x8*)(Bq + 8);
    }
    __syncthreads();
    s16x8 af[4], bfr[4];
#pragma unroll
    for (int i = 0; i < 4; ++i) {
      af[i]  = *(const s16x8*)&sA[(wm * 64 + i * 16 + l16) * 40 + quad * 8];
      bfr[i] = *(const s16x8*)&sB[(wn * 64 + i * 16 + l16) * 40 + quad * 8];
    }
#pragma unroll
    for (int mi = 0; mi < 4; ++mi)
#pragma unroll
      for (int ni = 0; ni < 4; ++ni)
        acc[mi][ni] = mfma16(af[mi], bfr[ni], acc[mi][ni]);
    __syncthreads();
  }

#pragma unroll
  for (int mi = 0; mi < 4; ++mi) {
#pragma unroll
    for (int ni = 0; ni < 4; ++ni) {
      const long n = n0 + wn * 64 + ni * 16 + l16;
      const float bv = bias[n];
#pragma unroll
      for (int i = 0; i < 4; ++i) {
        const long m = m0 + wm * 64 + mi * 16 + quad * 4 + i;
        float v = acc[mi][ni][i] + bv;
        if constexpr (ACT == 1) v = v > 0.f ? v : expm1f(v);
        if constexpr (ACT == 2) v = fmaxf(v, 0.f) + log1pf(expf(-fabsf(v))) + 0.1f;
        if constexpr (OBF) Cb[m * ldc + n] = f2bf(v);
        else               Cf[m * ldc + n] = v;
      }
    }
  }
}

// ---------------------------------------------------------------------------
// Persistent GRU recurrence, fence-free fabric-atomic protocol.
// 256 blocks x 512 thr (cooperative launch for co-residency only).
// Exchange = the fp32 hid[t] region itself (fresh address per step -> readers'
// L2 can never hold a stale line -> plain cached loads, no invalidation).
// All cross-XCD writes (hid) are device-scope atomicExch -> execute at L3,
// no dirty L2 in this kernel -> no wbl2/release fence ever needed.
// Barrier: per-block padded slots (atomicExch, zero contention) -> block 0
// polls all slots in parallel -> sets 8 padded go-flags -> blocks poll go.
// Values are monotonic step counts; slots zeroed each launch.
// LDS: sW 24x2050x2 = 98400 B (stride 1025 words, conflict-free)
//    + scr 8x24x17x4 = 13056 B -> 111.5 KB, 1 block/CU.
// ---------------------------------------------------------------------------
#define GRU_BLOCKS 256
#define UPB 8
#define WROWS 24
#define WSTR 2050

__global__ __launch_bounds__(512, 2)
void gru_persist(const unsigned short* __restrict__ gxb,  // [T,64,6144] bf16
                 const float* __restrict__ Whh,            // [6144,2048] f32
                 const float* __restrict__ bhh,            // [6144] f32
                 float* hid,                                // [T,64,2048] f32 out+exchange
                 unsigned* sy)                              // [256+8] padded sync slots
{
  __shared__ unsigned short sW[WROWS * WSTR];
  __shared__ float scr[8][24][17];
  const int tid  = threadIdx.x;
  const int lane = tid & 63;
  const int wave = tid >> 6;
  const int l16  = lane & 15, quad = lane >> 4;
  const int bt   = wave & 3;        // batch tile (16 rows)
  const int kh   = wave >> 2;       // K half (1024)
  const int jb   = blockIdx.x * UPB;

  // one-time stage: 24 rows of Whh (fp32 -> bf16) into LDS
  for (int wr = 0; wr < WROWS; ++wr) {
    const int gate = wr >> 3, u = wr & 7;
    const float* src = Whh + (long)(gate * CH_SZ + jb + u) * CH_SZ + tid * 4;
    f32x4 v = *(const f32x4*)src;
    s16x4 p;
    p[0] = (short)f2bf(v.x); p[1] = (short)f2bf(v.y);
    p[2] = (short)f2bf(v.z); p[3] = (short)f2bf(v.w);
    *(s16x4*)&sW[wr * WSTR + tid * 4] = p;
  }

  // per-thread epilogue constants: thread -> (batch row om, unit ou)
  const int om  = tid >> 3;          // 0..63
  const int ou  = tid & 7;           // 0..7
  const int oj  = jb + ou;
  const int obt = om >> 4, omi = om & 15;
  const float br_ = bhh[oj], bz_ = bhh[CH_SZ + oj], bn_ = bhh[2 * CH_SZ + oj];

  // B-fragment LDS base pointers (fixed for whole kernel)
  const unsigned short* w0 = &sW[l16 * WSTR + kh * 1024 + quad * 8];              // rows 0..15: r0..7,z0..7
  const unsigned short* w1 = &sW[(16 + (l16 & 7)) * WSTR + kh * 1024 + quad * 8]; // rows 16..23: n0..7 (dup)

  float ho = 0.f;                    // fp32 h_old register carry
  __syncthreads();

  for (int t = 0; t < T_STEPS; ++t) {
    // prefetch gate preactivations early; latency hides under MFMA loop
    const unsigned short* gxt = gxb + (long)t * (B_SZ * G3) + (long)om * G3 + oj;
    const unsigned short gxr = gxt[0];
    const unsigned short gxz = gxt[CH_SZ];
    const unsigned short gxn = gxt[2 * CH_SZ];

    if (t > 0) {
      // A-fragments straight from fp32 hid[t-1] (plain cached loads, fresh
      // region -> L2-shared among the 32 blocks of each XCD)
      const float* hb = hid + (long)(t - 1) * (B_SZ * CH_SZ)
                            + (long)(bt * 16 + l16) * CH_SZ + kh * 1024 + quad * 8;
      f32x4 a0 = {}, a1 = {};
      f32x4 P[8], Q[8];
#pragma unroll
      for (int u = 0; u < 4; ++u) {
        P[2 * u]     = *(const f32x4*)(hb + u * 32);
        P[2 * u + 1] = *(const f32x4*)(hb + u * 32 + 4);
      }
#pragma unroll
      for (int c = 0; c < 8; ++c) {
        f32x4* CUR = (c & 1) ? Q : P;   // c is unroll-constant -> static indexing
        f32x4* NXT = (c & 1) ? P : Q;
        if (c < 7) {
#pragma unroll
          for (int u = 0; u < 4; ++u) {
            NXT[2 * u]     = *(const f32x4*)(hb + ((c + 1) * 4 + u) * 32);
            NXT[2 * u + 1] = *(const f32x4*)(hb + ((c + 1) * 4 + u) * 32 + 4);
          }
        }
#pragma unroll
        for (int u = 0; u < 4; ++u) {
          const int s = c * 4 + u;
          s16x8 af = cvt8(CUR[2 * u], CUR[2 * u + 1]);
          a0 = mfma16(af, *(const s16x8*)(w0 + s * 32), a0);
          a1 = mfma16(af, *(const s16x8*)(w1 + s * 32), a1);
        }
      }
#pragma unroll
      for (int i = 0; i < 4; ++i) scr[wave][l16][quad * 4 + i] = a0[i];
      if (l16 < 8) {
#pragma unroll
        for (int i = 0; i < 4; ++i) scr[wave][16 + l16][quad * 4 + i] = a1[i];
      }
    }
    __syncthreads();

    float ghr = 0.f, ghz = 0.f, ghn = 0.f;
    if (t > 0) {
      ghr = scr[obt][ou][omi]      + scr[4 + obt][ou][omi];
      ghz = scr[obt][8 + ou][omi]  + scr[4 + obt][8 + ou][omi];
      ghn = scr[obt][16 + ou][omi] + scr[4 + obt][16 + ou][omi];
    }
    const float xr = bf2f(gxr), xz = bf2f(gxz), xn = bf2f(gxn);
    const float r = 1.f / (1.f + expf(-(xr + ghr + br_)));
    const float z = 1.f / (1.f + expf(-(xz + ghz + bz_)));
    const float n = tanhf(xn + r * (ghn + bn_));
    const float hv = (1.f - z) * n + z * ho;
    ho = hv;
    // device-scope atomic store -> lands at L3 (agent coherence point);
    // the only global write in this kernel, so L2 never holds dirty lines.
    atomicExch(&hid[(long)t * (B_SZ * CH_SZ) + (long)om * CH_SZ + oj], hv);

    if (t < T_STEPS - 1) {
      __syncthreads();               // emits vmcnt(0): hid atomics acked at L3
      const unsigned tv = (unsigned)(t + 1);
      if (blockIdx.x == 0) {
        if (tid >= 1 && tid < 256) { // parallel poll of all arrival slots
          while (__hip_atomic_load(&sy[tid * 16], __ATOMIC_RELAXED,
                                   __HIP_MEMORY_SCOPE_AGENT) < tv)
            __builtin_amdgcn_s_sleep(1);
        }
        __syncthreads();
        if (tid < 8) atomicExch(&sy[(256 + tid) * 16], tv);  // go-flags
      } else {
        if (tid == 0) {
          atomicExch(&sy[blockIdx.x * 16], tv);              // arrival
          while (__hip_atomic_load(&sy[(256 + (blockIdx.x & 7)) * 16],
                                   __ATOMIC_RELAXED, __HIP_MEMORY_SCOPE_AGENT) < tv)
            __builtin_amdgcn_s_sleep(1);
        }
        __syncthreads();
      }
      asm volatile("" ::: "memory");
    }
  }
}

__global__ void cast_f32_bf16(const float* __restrict__ s, unsigned short* __restrict__ d, long n) {
  long i = ((long)blockIdx.x * blockDim.x + threadIdx.x) * 4;
  if (i + 3 < n) {
    f32x4 v = *(const f32x4*)(s + i);
    s16x4 p;
    p[0] = (short)f2bf(v.x); p[1] = (short)f2bf(v.y);
    p[2] = (short)f2bf(v.z); p[3] = (short)f2bf(v.w);
    *(s16x4*)(d + i) = p;
  }
}

__global__ void zero_u32(unsigned int* p, int n) {
  int i = blockIdx.x * blockDim.x + threadIdx.x;
  if (i < n) p[i] = 0u;
}

extern "C" void kernel_launch(void* const* d_in, const int* in_sizes, int n_in,
                              void* d_out, int out_size, void* d_ws, size_t ws_size,
                              hipStream_t stream)
{
  const float* x    = (const float*)d_in[0];
  const float* We   = (const float*)d_in[1];
  const float* be   = (const float*)d_in[2];
  const float* Wih  = (const float*)d_in[3];
  const float* bih  = (const float*)d_in[4];
  const float* Whh  = (const float*)d_in[5];
  const float* bhh  = (const float*)d_in[6];
  const float* Wmu  = (const float*)d_in[7];
  const float* bmu  = (const float*)d_in[8];
  const float* Wsig = (const float*)d_in[9];
  const float* bsig = (const float*)d_in[10];

  float* out = (float*)d_out;
  float* mu  = out;
  float* sg  = out + (long)TB * DOUT;
  float* hid = out + 2L * TB * DOUT;

  // workspace layout (~251 MB)
  char* w = (char*)d_ws;
  unsigned short* Web  = (unsigned short*)w; w += (long)H_SZ * DIN * 2;
  unsigned short* Wihb = (unsigned short*)w; w += (long)G3 * H_SZ * 2;
  unsigned short* Wmub = (unsigned short*)w; w += (long)DOUT * H_SZ * 2;
  unsigned short* Wsgb = (unsigned short*)w; w += (long)DOUT * H_SZ * 2;
  unsigned short* xeb  = (unsigned short*)w; w += (long)TB * H_SZ * 2;
  unsigned short* gxb  = (unsigned short*)w; w += (long)TB * G3 * 2;
  unsigned*       sy   = (unsigned*)w;       w += 272 * 16 * 4;  // 256 slots + 8 go, 64B pad

  auto cast = [&](const float* s, unsigned short* d, long n) {
    int blocks = (int)((n / 4 + 255) / 256);
    cast_f32_bf16<<<blocks, 256, 0, stream>>>(s, d, n);
  };
  cast(We,   Web,  (long)H_SZ * DIN);
  cast(Wih,  Wihb, (long)G3 * H_SZ);
  cast(Wmu,  Wmub, (long)DOUT * H_SZ);
  cast(Wsig, Wsgb, (long)DOUT * H_SZ);
  zero_u32<<<17, 256, 0, stream>>>((unsigned int*)sy, 272 * 16);  // re-zeroed every launch/replay

  // enc: xe = elu(x @ We^T + be) -> bf16 [TB, H]
  gemm_bt<true, 1, true><<<dim3(TB / 128, H_SZ / 128), 256, 0, stream>>>(
      x, (long)DIN, Web, be, nullptr, xeb, (long)H_SZ, DIN);

  // gx = xe @ Wih^T + bih -> bf16 [TB, 6144]
  gemm_bt<false, 0, true><<<dim3(TB / 128, G3 / 128), 256, 0, stream>>>(
      xeb, (long)H_SZ, Wihb, bih, nullptr, gxb, (long)G3, H_SZ);

  // recurrence: persistent kernel; cooperative launch only for co-residency
  {
    void* kargs[] = {
      (void*)&gxb, (void*)&Whh, (void*)&bhh, (void*)&hid, (void*)&sy
    };
    hipLaunchCooperativeKernel((void*)gru_persist, dim3(GRU_BLOCKS), dim3(512),
                               kargs, 0, stream);
  }

  // heads
  gemm_bt<true, 1, false><<<dim3(TB / 128, DOUT / 128), 256, 0, stream>>>(
      hid, (long)CH_SZ, Wmub, bmu, mu, nullptr, (long)DOUT, H_SZ);
  gemm_bt<true, 2, false><<<dim3(TB / 128, DOUT / 128), 256, 0, stream>>>(
      hid + H_SZ, (long)CH_SZ, Wsgb, bsig, sg, nullptr, (long)DOUT, H_SZ);
}

// Round 4
// 5162.959 us; speedup vs baseline: 4.7479x; 1.0663x over previous
//
#include <hip/hip_runtime.h>
#include <hip/hip_bf16.h>
#include <math.h>

#define T_STEPS 256
#define B_SZ 64
#define DIN 512
#define H_SZ 1024
#define CH_SZ 2048
#define G3 6144
#define DOUT 512
#define TB 16384

typedef __attribute__((ext_vector_type(4))) float f32x4;
typedef __attribute__((ext_vector_type(8))) short s16x8;
typedef __attribute__((ext_vector_type(4))) short s16x4;
typedef __attribute__((ext_vector_type(8))) __bf16 bf16x8;

__device__ __forceinline__ unsigned short f2bf(float f) {
  unsigned u = __builtin_bit_cast(unsigned, f);
  u += 0x7fffu + ((u >> 16) & 1u);   // RNE
  return (unsigned short)(u >> 16);
}
__device__ __forceinline__ float bf2f(unsigned short h) {
  unsigned u = ((unsigned)h) << 16;
  return __builtin_bit_cast(float, u);
}
__device__ __forceinline__ f32x4 mfma16(s16x8 a, s16x8 b, f32x4 c) {
  return __builtin_amdgcn_mfma_f32_16x16x32_bf16(
      __builtin_bit_cast(bf16x8, a), __builtin_bit_cast(bf16x8, b), c, 0, 0, 0);
}

// ---------------------------------------------------------------------------
// C[M,N] = act(A[M,K] @ B[N,K]^T + bias[N]); unchanged verified GEMM.
// ---------------------------------------------------------------------------
template<bool AF32, int ACT, bool OBF>
__global__ __launch_bounds__(256, 2)
void gemm_bt(const void* __restrict__ Ap, long lda,
             const unsigned short* __restrict__ Bp,
             const float* __restrict__ bias,
             float* __restrict__ Cf, unsigned short* __restrict__ Cb, long ldc,
             int K)
{
  __shared__ unsigned short sA[128 * 40];
  __shared__ unsigned short sB[128 * 40];
  const int tid  = threadIdx.x;
  const int lane = tid & 63;
  const int wave = tid >> 6;
  const int wm = wave & 1, wn = wave >> 1;
  const int l16 = lane & 15, quad = lane >> 4;
  const long m0 = (long)blockIdx.x * 128;
  const long n0 = (long)blockIdx.y * 128;
  const int srow = tid >> 1;
  const int sseg = (tid & 1) << 4;

  f32x4 acc[4][4] = {};

  for (int k0 = 0; k0 < K; k0 += 32) {
    if constexpr (AF32) {
      const float* A = (const float*)Ap + (m0 + srow) * lda + (k0 + sseg);
      f32x4 v0 = *(const f32x4*)(A + 0);
      f32x4 v1 = *(const f32x4*)(A + 4);
      f32x4 v2 = *(const f32x4*)(A + 8);
      f32x4 v3 = *(const f32x4*)(A + 12);
      s16x8 p0, p1;
      p0[0] = (short)f2bf(v0.x); p0[1] = (short)f2bf(v0.y);
      p0[2] = (short)f2bf(v0.z); p0[3] = (short)f2bf(v0.w);
      p0[4] = (short)f2bf(v1.x); p0[5] = (short)f2bf(v1.y);
      p0[6] = (short)f2bf(v1.z); p0[7] = (short)f2bf(v1.w);
      p1[0] = (short)f2bf(v2.x); p1[1] = (short)f2bf(v2.y);
      p1[2] = (short)f2bf(v2.z); p1[3] = (short)f2bf(v2.w);
      p1[4] = (short)f2bf(v3.x); p1[5] = (short)f2bf(v3.y);
      p1[6] = (short)f2bf(v3.z); p1[7] = (short)f2bf(v3.w);
      *(s16x8*)&sA[srow * 40 + sseg]     = p0;
      *(s16x8*)&sA[srow * 40 + sseg + 8] = p1;
    } else {
      const unsigned short* A = (const unsigned short*)Ap + (m0 + srow) * lda + (k0 + sseg);
      *(s16x8*)&sA[srow * 40 + sseg]     = *(const s16x8*)(A);
      *(s16x8*)&sA[srow * 40 + sseg + 8] = *(const s16x8*)(A + 8);
    }
    {
      const unsigned short* Bq = Bp + (n0 + srow) * (long)K + (k0 + sseg);
      *(s16x8*)&sB[srow * 40 + sseg]     = *(const s16x8*)(Bq);
      *(s16x8*)&sB[srow * 40 + sseg + 8] = *(const s16x8*)(Bq + 8);
    }
    __syncthreads();
    s16x8 af[4], bfr[4];
#pragma unroll
    for (int i = 0; i < 4; ++i) {
      af[i]  = *(const s16x8*)&sA[(wm * 64 + i * 16 + l16) * 40 + quad * 8];
      bfr[i] = *(const s16x8*)&sB[(wn * 64 + i * 16 + l16) * 40 + quad * 8];
    }
#pragma unroll
    for (int mi = 0; mi < 4; ++mi)
#pragma unroll
      for (int ni = 0; ni < 4; ++ni)
        acc[mi][ni] = mfma16(af[mi], bfr[ni], acc[mi][ni]);
    __syncthreads();
  }

#pragma unroll
  for (int mi = 0; mi < 4; ++mi) {
#pragma unroll
    for (int ni = 0; ni < 4; ++ni) {
      const long n = n0 + wn * 64 + ni * 16 + l16;
      const float bv = bias[n];
#pragma unroll
      for (int i = 0; i < 4; ++i) {
        const long m = m0 + wm * 64 + mi * 16 + quad * 4 + i;
        float v = acc[mi][ni][i] + bv;
        if constexpr (ACT == 1) v = v > 0.f ? v : expm1f(v);
        if constexpr (ACT == 2) v = fmaxf(v, 0.f) + log1pf(expf(-fabsf(v))) + 0.1f;
        if constexpr (OBF) Cb[m * ldc + n] = f2bf(v);
        else               Cf[m * ldc + n] = v;
      }
    }
  }
}

// ---------------------------------------------------------------------------
// Persistent GRU recurrence, v3: bf16 exchange stream + 2-hop flat barrier.
// 256 blocks x 512 thr (cooperative launch for co-residency only).
// Exchange = hxb[t] bf16 stream (fresh address per step -> L2 never stale ->
// plain cached reads). Writes are packed-pair uint atomicExch -> execute at
// L3 coherence point; no dirty-L2 release fences anywhere (hid fp32 is plain
// stores, unread in-kernel, flushed at kernel end).
// Barrier (2 hops): each block atomicExch's its own padded slot; threads
// 0..255 of EVERY block poll all 256 slots in parallel; syncthreads.
// gx loads for t+1 are issued between arrival and poll -> latency hidden
// under the barrier wait.
// LDS: sW 24x2050x2 = 98400 B (stride 1025 words, conflict-free)
//    + scr 8x24x17x4 = 13056 B -> 111.5 KB, 1 block/CU.
// ---------------------------------------------------------------------------
#define GRU_BLOCKS 256
#define UPB 8
#define WROWS 24
#define WSTR 2050

__global__ __launch_bounds__(512, 2)
void gru_persist(const unsigned short* __restrict__ gxb,  // [T,64,6144] bf16
                 const float* __restrict__ Whh,            // [6144,2048] f32
                 const float* __restrict__ bhh,            // [6144] f32
                 float* hid,                                // [T,64,2048] f32 out
                 unsigned short* hxb,                       // [T,64,2048] bf16 exchange
                 unsigned* sy)                              // 256 padded sync slots
{
  __shared__ unsigned short sW[WROWS * WSTR];
  __shared__ float scr[8][24][17];
  const int tid  = threadIdx.x;
  const int lane = tid & 63;
  const int wave = tid >> 6;
  const int l16  = lane & 15, quad = lane >> 4;
  const int bt   = wave & 3;        // batch tile (16 rows)
  const int kh   = wave >> 2;       // K half (1024)
  const int jb   = blockIdx.x * UPB;

  // one-time stage: 24 rows of Whh (fp32 -> bf16) into LDS
  for (int wr = 0; wr < WROWS; ++wr) {
    const int gate = wr >> 3, u = wr & 7;
    const float* src = Whh + (long)(gate * CH_SZ + jb + u) * CH_SZ + tid * 4;
    f32x4 v = *(const f32x4*)src;
    s16x4 p;
    p[0] = (short)f2bf(v.x); p[1] = (short)f2bf(v.y);
    p[2] = (short)f2bf(v.z); p[3] = (short)f2bf(v.w);
    *(s16x4*)&sW[wr * WSTR + tid * 4] = p;
  }

  // per-thread epilogue constants: thread -> (batch row om, unit ou)
  const int om  = tid >> 3;          // 0..63
  const int ou  = tid & 7;           // 0..7
  const int oj  = jb + ou;
  const int obt = om >> 4, omi = om & 15;
  const float br_ = bhh[oj], bz_ = bhh[CH_SZ + oj], bn_ = bhh[2 * CH_SZ + oj];

  // B-fragment LDS base pointers (fixed for whole kernel)
  const unsigned short* w0 = &sW[l16 * WSTR + kh * 1024 + quad * 8];              // rows 0..15: r0..7,z0..7
  const unsigned short* w1 = &sW[(16 + (l16 & 7)) * WSTR + kh * 1024 + quad * 8]; // rows 16..23: n0..7 (dup)

  float ho = 0.f;                    // fp32 h_old register carry
  // gx preactivations for t=0 (prefetched; later steps load under the barrier)
  unsigned short gxr, gxz, gxn;
  {
    const unsigned short* g0 = gxb + (long)om * G3 + oj;
    gxr = g0[0]; gxz = g0[CH_SZ]; gxn = g0[2 * CH_SZ];
  }
  __syncthreads();

  for (int t = 0; t < T_STEPS; ++t) {
    if (t > 0) {
      // A-fragments from bf16 hxb[t-1] (plain cached loads, fresh region,
      // L2-shared among the 32 blocks of each XCD). 32 loads, depth-2 pipe.
      const unsigned short* hb = hxb + (long)(t - 1) * (B_SZ * CH_SZ)
                               + (long)(bt * 16 + l16) * CH_SZ + kh * 1024 + quad * 8;
      s16x8 P[8], Q[8];
      f32x4 a0 = {}, a1 = {};
#pragma unroll
      for (int u = 0; u < 8; ++u) P[u] = *(const s16x8*)(hb + u * 32);
#pragma unroll
      for (int c = 0; c < 4; ++c) {
        s16x8* CUR = (c & 1) ? Q : P;   // c is unroll-constant -> static indexing
        s16x8* NXT = (c & 1) ? P : Q;
        if (c < 3) {
#pragma unroll
          for (int u = 0; u < 8; ++u)
            NXT[u] = *(const s16x8*)(hb + ((c + 1) * 8 + u) * 32);
        }
#pragma unroll
        for (int u = 0; u < 8; ++u) {
          const int s = c * 8 + u;
          a0 = mfma16(CUR[u], *(const s16x8*)(w0 + s * 32), a0);
          a1 = mfma16(CUR[u], *(const s16x8*)(w1 + s * 32), a1);
        }
      }
#pragma unroll
      for (int i = 0; i < 4; ++i) scr[wave][l16][quad * 4 + i] = a0[i];
      if (l16 < 8) {
#pragma unroll
        for (int i = 0; i < 4; ++i) scr[wave][16 + l16][quad * 4 + i] = a1[i];
      }
    }
    __syncthreads();

    float ghr = 0.f, ghz = 0.f, ghn = 0.f;
    if (t > 0) {
      ghr = scr[obt][ou][omi]      + scr[4 + obt][ou][omi];
      ghz = scr[obt][8 + ou][omi]  + scr[4 + obt][8 + ou][omi];
      ghn = scr[obt][16 + ou][omi] + scr[4 + obt][16 + ou][omi];
    }
    const float xr = bf2f(gxr), xz = bf2f(gxz), xn = bf2f(gxn);
    const float r = 1.f / (1.f + expf(-(xr + ghr + br_)));
    const float z = 1.f / (1.f + expf(-(xz + ghz + bz_)));
    const float n = tanhf(xn + r * (ghn + bn_));
    const float hv = (1.f - z) * n + z * ho;
    ho = hv;
    hid[(long)t * (B_SZ * CH_SZ) + (long)om * CH_SZ + oj] = hv;   // plain store

    // exchange: pack (j, j+1) into one uint, even lanes atomicExch -> L3
    const float hvn = __shfl_down(hv, 1);
    if ((lane & 1) == 0) {
      unsigned pk;
      asm("v_cvt_pk_bf16_f32 %0, %1, %2" : "=v"(pk) : "v"(hv), "v"(hvn));
      atomicExch((unsigned*)(hxb + (long)t * (B_SZ * CH_SZ) + (long)om * CH_SZ + oj), pk);
    }

    if (t < T_STEPS - 1) {
      __syncthreads();               // vmcnt(0): exchange atomics acked at L3
      const unsigned tv = (unsigned)(t + 1);
      if (tid == 0) atomicExch(&sy[blockIdx.x * 16], tv);    // arrival
      // gx prefetch for t+1 -- latency hides under the poll
      const unsigned short* g1 = gxb + (long)tv * (B_SZ * G3) + (long)om * G3 + oj;
      const unsigned short nr = g1[0], nz = g1[CH_SZ], nn = g1[2 * CH_SZ];
      if (tid < 256) {               // flat poll: every block watches all slots
        while (__hip_atomic_load(&sy[tid * 16], __ATOMIC_RELAXED,
                                 __HIP_MEMORY_SCOPE_AGENT) < tv)
          __builtin_amdgcn_s_sleep(2);
      }
      __syncthreads();
      asm volatile("" ::: "memory");
      gxr = nr; gxz = nz; gxn = nn;
    }
  }
}

__global__ void cast_f32_bf16(const float* __restrict__ s, unsigned short* __restrict__ d, long n) {
  long i = ((long)blockIdx.x * blockDim.x + threadIdx.x) * 4;
  if (i + 3 < n) {
    f32x4 v = *(const f32x4*)(s + i);
    s16x4 p;
    p[0] = (short)f2bf(v.x); p[1] = (short)f2bf(v.y);
    p[2] = (short)f2bf(v.z); p[3] = (short)f2bf(v.w);
    *(s16x4*)(d + i) = p;
  }
}

__global__ void zero_u32(unsigned int* p, int n) {
  int i = blockIdx.x * blockDim.x + threadIdx.x;
  if (i < n) p[i] = 0u;
}

extern "C" void kernel_launch(void* const* d_in, const int* in_sizes, int n_in,
                              void* d_out, int out_size, void* d_ws, size_t ws_size,
                              hipStream_t stream)
{
  const float* x    = (const float*)d_in[0];
  const float* We   = (const float*)d_in[1];
  const float* be   = (const float*)d_in[2];
  const float* Wih  = (const float*)d_in[3];
  const float* bih  = (const float*)d_in[4];
  const float* Whh  = (const float*)d_in[5];
  const float* bhh  = (const float*)d_in[6];
  const float* Wmu  = (const float*)d_in[7];
  const float* bmu  = (const float*)d_in[8];
  const float* Wsig = (const float*)d_in[9];
  const float* bsig = (const float*)d_in[10];

  float* out = (float*)d_out;
  float* mu  = out;
  float* sg  = out + (long)TB * DOUT;
  float* hid = out + 2L * TB * DOUT;

  // workspace layout (~315 MB)
  char* w = (char*)d_ws;
  unsigned short* Web  = (unsigned short*)w; w += (long)H_SZ * DIN * 2;
  unsigned short* Wihb = (unsigned short*)w; w += (long)G3 * H_SZ * 2;
  unsigned short* Wmub = (unsigned short*)w; w += (long)DOUT * H_SZ * 2;
  unsigned short* Wsgb = (unsigned short*)w; w += (long)DOUT * H_SZ * 2;
  unsigned short* xeb  = (unsigned short*)w; w += (long)TB * H_SZ * 2;
  unsigned short* gxb  = (unsigned short*)w; w += (long)TB * G3 * 2;
  unsigned short* hxb  = (unsigned short*)w; w += (long)T_STEPS * B_SZ * CH_SZ * 2;
  unsigned*       sy   = (unsigned*)w;       w += 272 * 16 * 4;  // padded sync slots

  auto cast = [&](const float* s, unsigned short* d, long n) {
    int blocks = (int)((n / 4 + 255) / 256);
    cast_f32_bf16<<<blocks, 256, 0, stream>>>(s, d, n);
  };
  cast(We,   Web,  (long)H_SZ * DIN);
  cast(Wih,  Wihb, (long)G3 * H_SZ);
  cast(Wmu,  Wmub, (long)DOUT * H_SZ);
  cast(Wsig, Wsgb, (long)DOUT * H_SZ);
  zero_u32<<<17, 256, 0, stream>>>((unsigned int*)sy, 272 * 16);  // re-zeroed every launch/replay

  // enc: xe = elu(x @ We^T + be) -> bf16 [TB, H]
  gemm_bt<true, 1, true><<<dim3(TB / 128, H_SZ / 128), 256, 0, stream>>>(
      x, (long)DIN, Web, be, nullptr, xeb, (long)H_SZ, DIN);

  // gx = xe @ Wih^T + bih -> bf16 [TB, 6144]
  gemm_bt<false, 0, true><<<dim3(TB / 128, G3 / 128), 256, 0, stream>>>(
      xeb, (long)H_SZ, Wihb, bih, nullptr, gxb, (long)G3, H_SZ);

  // recurrence: persistent kernel; cooperative launch only for co-residency
  {
    void* kargs[] = {
      (void*)&gxb, (void*)&Whh, (void*)&bhh, (void*)&hid, (void*)&hxb, (void*)&sy
    };
    hipLaunchCooperativeKernel((void*)gru_persist, dim3(GRU_BLOCKS), dim3(512),
                               kargs, 0, stream);
  }

  // heads
  gemm_bt<true, 1, false><<<dim3(TB / 128, DOUT / 128), 256, 0, stream>>>(
      hid, (long)CH_SZ, Wmub, bmu, mu, nullptr, (long)DOUT, H_SZ);
  gemm_bt<true, 2, false><<<dim3(TB / 128, DOUT / 128), 256, 0, stream>>>(
      hid + H_SZ, (long)CH_SZ, Wsgb, bsig, sg, nullptr, (long)DOUT, H_SZ);
}